// Round 16
// baseline (14.074 us; speedup 1.0000x reference)
//
#include <hip/hip_runtime.h>
#include <math.h>

#define B_ 8
#define U_ 512
#define T_ 1024
#define H_ 512
#define D_ 128
#define K_ 10

#define UT 16     // u rows per block / scan tile size
#define TC 32     // t chunk size
#define NT2 32    // tiles per batch (U_/UT)

typedef __attribute__((ext_vector_type(8))) short bf16x8;
typedef __attribute__((ext_vector_type(4))) float f32x4;

__device__ __forceinline__ unsigned short f32_to_bf16_rtne(float f) {
    unsigned u = __float_as_uint(f);
    unsigned r = u + 0x7FFFu + ((u >> 16) & 1u);
    return (unsigned short)(r >> 16);
}
__device__ __forceinline__ unsigned pack_bf16(float a, float b) {
    return (unsigned)f32_to_bf16_rtne(a) | ((unsigned)f32_to_bf16_rtne(b) << 16);
}

// Self-validating tile-total flag (see R12): u64 {hi=bits(v)^sign, lo=bits(v)}.
__device__ __forceinline__ unsigned long long pack_flag(float v) {
    unsigned lo = __float_as_uint(v);
    return ((unsigned long long)(lo ^ 0x80000000u) << 32) | lo;
}
__device__ __forceinline__ bool unpack_flag(unsigned long long g, float* v) {
    unsigned lo = (unsigned)g, hi = (unsigned)(g >> 32);
    *v = __uint_as_float(lo);
    return (hi == (lo ^ 0x80000000u)) && (*v > 0.f);
}

// ---------------- Fused kernel: prep (MFMA GEMM) + lookback + attend --------
// R16 = R14 with ctx LDS staging deleted: PV reads ctx directly from L2
// (coalesced 512B/wave segments). LDS pipe now carries only phi broadcasts;
// ctx moves to the parallel VMEM pipe. Same values, same summation order.
__global__ __launch_bounds__(512, 1)
void fused_kernel(const float* __restrict__ h_t,
                  const float* __restrict__ ctx,
                  const float* __restrict__ mask,
                  const float* __restrict__ W,
                  const float* __restrict__ bias,
                  float* __restrict__ out,
                  unsigned long long* __restrict__ Tg) { // [B][NT2][K]
    __shared__ unsigned short A_s[16 * 512];   // 16 KB, XOR-swizzled rows
    __shared__ float Cp[4][16][33];            // K-quarter partials, +1 pad
    __shared__ float ab_s[16][20];             // alpha[k], beta[10+k]
    __shared__ float kin_s[16][K_];            // kinc, later kappa
    __shared__ float L_s[16][K_];              // tile-local inclusive sums
    __shared__ float part_s[NT2][K_];          // lookback partials
    __shared__ float pre_s[K_];
    __shared__ float phi_s[16][TC + 4];
    __shared__ float red_lo[160], red_hi[160];

    int tid = threadIdx.x;
    int lane = tid & 63;
    int w = tid >> 6;                          // 0..7
    int b = blockIdx.x >> 5;
    int mytile = blockIdx.x & 31;
    int row0 = b * U_ + mytile * UT;           // global h_t row of tile start

    // ---- B fragments: 4 per wave (K-quarter), held in VGPRs (W L2-resident)
    int kq = w >> 1;                           // K quarter (128 each)
    int ntile = w & 1;                         // 16-col N tile
    int c = 16 * ntile + (lane & 15);
    int kb = kq * 128 + ((lane >> 4) << 3);
    bf16x8 bfrag[4];
    #pragma unroll
    for (int s = 0; s < 4; ++s) {
        #pragma unroll
        for (int e = 0; e < 8; ++e) {
            float wv = (c < 30) ? W[(size_t)(kb + 32 * s + e) * 30 + c] : 0.f;
            bfrag[s][e] = (short)f32_to_bf16_rtne(wv);
        }
    }

    // ---- stage A (16 rows): thread -> row r=tid>>5, k-chunk (tid&31)*16
    {
        int r = tid >> 5;
        int kc = (tid & 31) * 16;              // f32 elems
        const float4* src = (const float4*)(h_t + (size_t)(row0 + r) * H_ + kc);
        unsigned pk[8];
        #pragma unroll
        for (int i = 0; i < 4; ++i) {
            float4 v = src[i];
            pk[2 * i]     = pack_bf16(v.x, v.y);
            pk[2 * i + 1] = pack_bf16(v.z, v.w);
        }
        int base = r * 1024 + kc * 2;          // byte offset
        int swz = (r & 7) << 4;
        *(int4*)((char*)A_s + ((base) ^ swz)) =
            make_int4((int)pk[0], (int)pk[1], (int)pk[2], (int)pk[3]);
        *(int4*)((char*)A_s + ((base + 16) ^ swz)) =
            make_int4((int)pk[4], (int)pk[5], (int)pk[6], (int)pk[7]);
    }
    __syncthreads();

    // ---- MFMA: M=16, wave = (kq, ntile), 4 K-steps
    {
        int ar = lane & 15;
        int abase = ar * 1024 + (kq * 128 + ((lane >> 4) << 3)) * 2;
        int aswz = (ar & 7) << 4;
        f32x4 acc = {0.f, 0.f, 0.f, 0.f};
        #pragma unroll
        for (int s = 0; s < 4; ++s) {
            bf16x8 af = *(const bf16x8*)((const char*)A_s + ((abase + s * 64) ^ aswz));
            acc = __builtin_amdgcn_mfma_f32_16x16x32_bf16(af, bfrag[s], acc, 0, 0, 0);
        }
        int rbase = (lane >> 4) * 4;           // C/D: col=lane&15, row=rbase+r
        int ccol = 16 * ntile + (lane & 15);
        #pragma unroll
        for (int r = 0; r < 4; ++r)
            Cp[kq][rbase + r][ccol] = acc[r];
    }
    __syncthreads();

    // ---- combine K-quarters, exp, route (16x30 outputs)
    if (tid < 480) {
        int rr = tid / 30, cc = tid % 30;
        float dot = (Cp[0][rr][cc] + Cp[1][rr][cc]) + (Cp[2][rr][cc] + Cp[3][rr][cc]);
        float p = __expf(dot + bias[cc]);
        if (cc < 20) ab_s[rr][cc] = p;
        else         kin_s[rr][cc - 20] = 0.2f * p;
    }
    __syncthreads();

    // ---- tile-local scan (16 rows) + publish packed total
    if (tid < UT * K_) {
        int u_l = tid / K_, k = tid % K_;
        float ssum = 0.f;
        for (int r = 0; r <= u_l; ++r) ssum += kin_s[r][k];
        L_s[u_l][k] = ssum;
        if (u_l == UT - 1)
            __hip_atomic_store(&Tg[((size_t)b * NT2 + mytile) * K_ + k],
                               pack_flag(ssum),
                               __ATOMIC_RELAXED, __HIP_MEMORY_SCOPE_AGENT);
    }
    __syncthreads();

    // ---- decoupled lookback: 32-way parallel, <=1 slot per thread
    if (tid < NT2 * K_) {
        int jg = tid / K_, k = tid % K_;
        float v = 0.f;
        if (jg < mytile) {
            const unsigned long long* p = &Tg[((size_t)b * NT2 + jg) * K_ + k];
            for (;;) {
                unsigned long long g = __hip_atomic_load(p, __ATOMIC_RELAXED,
                                                         __HIP_MEMORY_SCOPE_AGENT);
                if (unpack_flag(g, &v)) break;
                __builtin_amdgcn_s_sleep(1);
            }
        }
        part_s[jg][k] = v;
    }
    __syncthreads();
    if (tid < K_) {
        float pre = 0.f;
        #pragma unroll
        for (int jg = 0; jg < NT2; ++jg) pre += part_s[jg][tid];  // fixed order
        pre_s[tid] = pre;
    }
    __syncthreads();

    // ---- finalize kappa; per-u active-window bounds (radius exp(-20))
    if (tid < UT * K_) {
        int u_l = tid / K_, k = tid % K_;
        float kv = pre_s[k] + L_s[u_l][k];
        kin_s[u_l][k] = kv;                    // kin_s now holds kappa
        float bvv = ab_s[u_l][10 + k];
        float r = sqrtf(20.f / bvv);           // truncation radius; tail ~1e-6
        red_lo[tid] = kv - r; red_hi[tid] = kv + r;
    }
    __syncthreads();
    if (tid < 64) {
        float l = fminf(red_lo[tid], red_lo[tid + 64]);
        float h = fmaxf(red_hi[tid], red_hi[tid + 64]);
        if (tid < 32) { l = fminf(l, red_lo[tid + 128]); h = fmaxf(h, red_hi[tid + 128]); }
        #pragma unroll
        for (int d = 32; d > 0; d >>= 1) {
            l = fminf(l, __shfl_xor(l, d, 64));
            h = fmaxf(h, __shfl_xor(h, d, 64));
        }
        if (tid == 0) { red_lo[0] = l; red_hi[0] = h; }
    }
    __syncthreads();
    int t_begin = max(0, (int)floorf(red_lo[0]));   // exact, no align-down
    int t_end   = min(T_, (int)ceilf(red_hi[0]) + 1);

    // ---- attend: phi via LDS broadcast; ctx direct from L2 in PV
    int u2 = tid >> 5;                         // 0..7 (PV rows {u2, u2+8})
    int g  = tid & 31;
    const float* cbase = ctx + ((size_t)b * T_) * D_ + 4 * g;
    float a0[4] = {0.f, 0.f, 0.f, 0.f};
    float a1[4] = {0.f, 0.f, 0.f, 0.f};

    for (int t0 = t_begin; t0 < t_end; t0 += TC) {
        __syncthreads();                       // protect phi_s from prev readers
        // phi: 16xTC = 512 values, 1 per thread; zero beyond T
        {
            int uu = tid >> 5;                 // 0..15
            int tl = tid & 31;
            int tf_i = t0 + tl;
            float tf = (float)tf_i;
            float ph = 0.f;
            #pragma unroll
            for (int k = 0; k < K_; ++k) {
                float d = kin_s[uu][k] - tf;
                float x = ab_s[uu][10 + k] * d * d;
                ph += ab_s[uu][k] * __expf(-x);
            }
            int tm = min(tf_i, T_ - 1);
            ph = (tf_i < T_) ? ph * mask[(size_t)b * T_ + tm] : 0.f;
            phi_s[uu][tl] = ph;
        }
        __syncthreads();
        if (tid < 256) {
            #pragma unroll 2
            for (int tl4 = 0; tl4 < TC / 4; ++tl4) {
                float4 p0 = *(const float4*)(&phi_s[u2][4 * tl4]);
                float4 p1 = *(const float4*)(&phi_s[u2 + 8][4 * tl4]);
                #pragma unroll
                for (int qq = 0; qq < 4; ++qq) {
                    float f0 = (qq == 0) ? p0.x : (qq == 1) ? p0.y : (qq == 2) ? p0.z : p0.w;
                    float f1 = (qq == 0) ? p1.x : (qq == 1) ? p1.y : (qq == 2) ? p1.z : p1.w;
                    int tc = min(t0 + 4 * tl4 + qq, T_ - 1);   // phi=0 past T
                    float4 c0 = *(const float4*)(cbase + (size_t)tc * D_);
                    a0[0] += f0 * c0.x; a0[1] += f0 * c0.y;
                    a0[2] += f0 * c0.z; a0[3] += f0 * c0.w;
                    a1[0] += f1 * c0.x; a1[1] += f1 * c0.y;
                    a1[2] += f1 * c0.z; a1[3] += f1 * c0.w;
                }
            }
        }
    }

    if (tid < 256) {
        float* orow0 = out + ((size_t)(b * U_ + mytile * UT) + u2) * D_;
        float* orow1 = out + ((size_t)(b * U_ + mytile * UT) + u2 + 8) * D_;
        *(float4*)(orow0 + 4 * g) = make_float4(a0[0], a0[1], a0[2], a0[3]);
        *(float4*)(orow1 + 4 * g) = make_float4(a1[0], a1[1], a1[2], a1[3]);
    }
}

extern "C" void kernel_launch(void* const* d_in, const int* in_sizes, int n_in,
                              void* d_out, int out_size, void* d_ws, size_t ws_size,
                              hipStream_t stream) {
    const float* h_t  = (const float*)d_in[0];
    const float* ctx  = (const float*)d_in[1];
    const float* mask = (const float*)d_in[2];
    const float* W    = (const float*)d_in[3];
    const float* bias = (const float*)d_in[4];
    float* out = (float*)d_out;
    unsigned long long* Tg = (unsigned long long*)d_ws;  // B*NT2*K u64 = 20 KB

    fused_kernel<<<dim3(B_ * NT2), dim3(512), 0, stream>>>(
        h_t, ctx, mask, W, bias, out, Tg);
}

// Round 17
// 13.025 us; speedup vs baseline: 1.0805x; 1.0805x over previous
//
#include <hip/hip_runtime.h>
#include <math.h>

#define B_ 8
#define U_ 512
#define T_ 1024
#define H_ 512
#define D_ 128
#define K_ 10

#define UT 16     // u rows per block / scan tile size
#define TC 32     // t chunk size
#define NT2 32    // tiles per batch (U_/UT)

typedef __attribute__((ext_vector_type(8))) short bf16x8;
typedef __attribute__((ext_vector_type(4))) float f32x4;

__device__ __forceinline__ unsigned short f32_to_bf16_rtne(float f) {
    unsigned u = __float_as_uint(f);
    unsigned r = u + 0x7FFFu + ((u >> 16) & 1u);
    return (unsigned short)(r >> 16);
}
__device__ __forceinline__ unsigned pack_bf16(float a, float b) {
    return (unsigned)f32_to_bf16_rtne(a) | ((unsigned)f32_to_bf16_rtne(b) << 16);
}

// Self-validating tile-total flag (see R12): u64 {hi=bits(v)^sign, lo=bits(v)}.
__device__ __forceinline__ unsigned long long pack_flag(float v) {
    unsigned lo = __float_as_uint(v);
    return ((unsigned long long)(lo ^ 0x80000000u) << 32) | lo;
}
__device__ __forceinline__ bool unpack_flag(unsigned long long g, float* v) {
    unsigned lo = (unsigned)g, hi = (unsigned)(g >> 32);
    *v = __uint_as_float(lo);
    return (hi == (lo ^ 0x80000000u)) && (*v > 0.f);
}

// ---------------- Fused kernel: prep (MFMA GEMM) + lookback + attend --------
// R17 = R14 (best measured: 13.05us). Block = 16 u-rows, 256 blocks x 512 thr.
// Single-node graph; decoupled-lookback cumsum via self-validating flags;
// MFMA params GEMM; truncation radius exp(-20); LDS-staged attend with
// 2-rows-per-thread PV. R15 (pipelined attend) and R16 (direct-L2 PV) both
// regressed vs this form -- attend is balanced across pipes at 1 block/CU.
__global__ __launch_bounds__(512, 1)
void fused_kernel(const float* __restrict__ h_t,
                  const float* __restrict__ ctx,
                  const float* __restrict__ mask,
                  const float* __restrict__ W,
                  const float* __restrict__ bias,
                  float* __restrict__ out,
                  unsigned long long* __restrict__ Tg) { // [B][NT2][K]
    __shared__ unsigned short A_s[16 * 512];   // 16 KB, XOR-swizzled rows
    __shared__ float Cp[4][16][33];            // K-quarter partials, +1 pad
    __shared__ float ab_s[16][20];             // alpha[k], beta[10+k]
    __shared__ float kin_s[16][K_];            // kinc, later kappa
    __shared__ float L_s[16][K_];              // tile-local inclusive sums
    __shared__ float part_s[NT2][K_];          // lookback partials
    __shared__ float pre_s[K_];
    __shared__ float phi_s[16][TC + 4];
    __shared__ float ctx_s[TC][D_];            // 16 KB
    __shared__ float red_lo[160], red_hi[160];

    int tid = threadIdx.x;
    int lane = tid & 63;
    int w = tid >> 6;                          // 0..7
    int b = blockIdx.x >> 5;
    int mytile = blockIdx.x & 31;
    int row0 = b * U_ + mytile * UT;           // global h_t row of tile start

    // ---- B fragments: 4 per wave (K-quarter), held in VGPRs (W L2-resident)
    int kq = w >> 1;                           // K quarter (128 each)
    int ntile = w & 1;                         // 16-col N tile
    int c = 16 * ntile + (lane & 15);
    int kb = kq * 128 + ((lane >> 4) << 3);
    bf16x8 bfrag[4];
    #pragma unroll
    for (int s = 0; s < 4; ++s) {
        #pragma unroll
        for (int e = 0; e < 8; ++e) {
            float wv = (c < 30) ? W[(size_t)(kb + 32 * s + e) * 30 + c] : 0.f;
            bfrag[s][e] = (short)f32_to_bf16_rtne(wv);
        }
    }

    // ---- stage A (16 rows): thread -> row r=tid>>5, k-chunk (tid&31)*16
    {
        int r = tid >> 5;
        int kc = (tid & 31) * 16;              // f32 elems
        const float4* src = (const float4*)(h_t + (size_t)(row0 + r) * H_ + kc);
        unsigned pk[8];
        #pragma unroll
        for (int i = 0; i < 4; ++i) {
            float4 v = src[i];
            pk[2 * i]     = pack_bf16(v.x, v.y);
            pk[2 * i + 1] = pack_bf16(v.z, v.w);
        }
        int base = r * 1024 + kc * 2;          // byte offset
        int swz = (r & 7) << 4;
        *(int4*)((char*)A_s + ((base) ^ swz)) =
            make_int4((int)pk[0], (int)pk[1], (int)pk[2], (int)pk[3]);
        *(int4*)((char*)A_s + ((base + 16) ^ swz)) =
            make_int4((int)pk[4], (int)pk[5], (int)pk[6], (int)pk[7]);
    }
    __syncthreads();

    // ---- MFMA: M=16, wave = (kq, ntile), 4 K-steps
    {
        int ar = lane & 15;
        int abase = ar * 1024 + (kq * 128 + ((lane >> 4) << 3)) * 2;
        int aswz = (ar & 7) << 4;
        f32x4 acc = {0.f, 0.f, 0.f, 0.f};
        #pragma unroll
        for (int s = 0; s < 4; ++s) {
            bf16x8 af = *(const bf16x8*)((const char*)A_s + ((abase + s * 64) ^ aswz));
            acc = __builtin_amdgcn_mfma_f32_16x16x32_bf16(af, bfrag[s], acc, 0, 0, 0);
        }
        int rbase = (lane >> 4) * 4;           // C/D: col=lane&15, row=rbase+r
        int ccol = 16 * ntile + (lane & 15);
        #pragma unroll
        for (int r = 0; r < 4; ++r)
            Cp[kq][rbase + r][ccol] = acc[r];
    }
    __syncthreads();

    // ---- combine K-quarters, exp, route (16x30 outputs)
    if (tid < 480) {
        int rr = tid / 30, cc = tid % 30;
        float dot = (Cp[0][rr][cc] + Cp[1][rr][cc]) + (Cp[2][rr][cc] + Cp[3][rr][cc]);
        float p = __expf(dot + bias[cc]);
        if (cc < 20) ab_s[rr][cc] = p;
        else         kin_s[rr][cc - 20] = 0.2f * p;
    }
    __syncthreads();

    // ---- tile-local scan (16 rows) + publish packed total
    if (tid < UT * K_) {
        int u_l = tid / K_, k = tid % K_;
        float ssum = 0.f;
        for (int r = 0; r <= u_l; ++r) ssum += kin_s[r][k];
        L_s[u_l][k] = ssum;
        if (u_l == UT - 1)
            __hip_atomic_store(&Tg[((size_t)b * NT2 + mytile) * K_ + k],
                               pack_flag(ssum),
                               __ATOMIC_RELAXED, __HIP_MEMORY_SCOPE_AGENT);
    }
    __syncthreads();

    // ---- decoupled lookback: 32-way parallel, <=1 slot per thread
    if (tid < NT2 * K_) {
        int jg = tid / K_, k = tid % K_;
        float v = 0.f;
        if (jg < mytile) {
            const unsigned long long* p = &Tg[((size_t)b * NT2 + jg) * K_ + k];
            for (;;) {
                unsigned long long g = __hip_atomic_load(p, __ATOMIC_RELAXED,
                                                         __HIP_MEMORY_SCOPE_AGENT);
                if (unpack_flag(g, &v)) break;
                __builtin_amdgcn_s_sleep(1);
            }
        }
        part_s[jg][k] = v;
    }
    __syncthreads();
    if (tid < K_) {
        float pre = 0.f;
        #pragma unroll
        for (int jg = 0; jg < NT2; ++jg) pre += part_s[jg][tid];  // fixed order
        pre_s[tid] = pre;
    }
    __syncthreads();

    // ---- finalize kappa; per-u active-window bounds (radius exp(-20))
    if (tid < UT * K_) {
        int u_l = tid / K_, k = tid % K_;
        float kv = pre_s[k] + L_s[u_l][k];
        kin_s[u_l][k] = kv;                    // kin_s now holds kappa
        float bvv = ab_s[u_l][10 + k];
        float r = sqrtf(20.f / bvv);           // truncation radius; tail ~1e-6
        red_lo[tid] = kv - r; red_hi[tid] = kv + r;
    }
    __syncthreads();
    if (tid < 64) {
        float l = fminf(red_lo[tid], red_lo[tid + 64]);
        float h = fmaxf(red_hi[tid], red_hi[tid + 64]);
        if (tid < 32) { l = fminf(l, red_lo[tid + 128]); h = fmaxf(h, red_hi[tid + 128]); }
        #pragma unroll
        for (int d = 32; d > 0; d >>= 1) {
            l = fminf(l, __shfl_xor(l, d, 64));
            h = fmaxf(h, __shfl_xor(h, d, 64));
        }
        if (tid == 0) { red_lo[0] = l; red_hi[0] = h; }
    }
    __syncthreads();
    int t_begin = max(0, (int)floorf(red_lo[0]));   // exact, no align-down
    int t_end   = min(T_, (int)ceilf(red_hi[0]) + 1);

    // ---- attend: phi (512 thr) + masked matmul (256 thr x 2 rows)
    int u2 = tid >> 5;                         // 0..7 (PV), rows {u2, u2+8}
    int g  = tid & 31;
    float a0[4] = {0.f, 0.f, 0.f, 0.f};
    float a1[4] = {0.f, 0.f, 0.f, 0.f};

    for (int t0 = t_begin; t0 < t_end; t0 += TC) {
        __syncthreads();
        // stage ctx chunk (per-row float4, rows clamped to T-1), 2 slots/thread
        {
            #pragma unroll
            for (int i = 0; i < (TC * D_ / 4) / 512; ++i) {
                int slot = tid + 512 * i;
                int r = slot >> 5;                      // 0..TC-1
                int rc = min(t0 + r, T_ - 1);
                const float4* src = (const float4*)(ctx + ((size_t)b * T_ + rc) * D_);
                ((float4*)(&ctx_s[0][0]))[slot] = src[slot & 31];
            }
        }
        // phi: 16xTC = 512 values, 1 per thread; zero beyond T
        {
            int uu = tid >> 5;                 // 0..15
            int tl = tid & 31;
            int tf_i = t0 + tl;
            float tf = (float)tf_i;
            float ph = 0.f;
            #pragma unroll
            for (int k = 0; k < K_; ++k) {
                float d = kin_s[uu][k] - tf;
                float x = ab_s[uu][10 + k] * d * d;
                ph += ab_s[uu][k] * __expf(-x);
            }
            int tm = min(tf_i, T_ - 1);
            ph = (tf_i < T_) ? ph * mask[(size_t)b * T_ + tm] : 0.f;
            phi_s[uu][tl] = ph;
        }
        __syncthreads();
        if (tid < 256) {
            for (int tl4 = 0; tl4 < TC / 4; ++tl4) {
                float4 p0 = *(const float4*)(&phi_s[u2][4 * tl4]);
                float4 p1 = *(const float4*)(&phi_s[u2 + 8][4 * tl4]);
                #pragma unroll
                for (int qq = 0; qq < 4; ++qq) {
                    float f0 = (qq == 0) ? p0.x : (qq == 1) ? p0.y : (qq == 2) ? p0.z : p0.w;
                    float f1 = (qq == 0) ? p1.x : (qq == 1) ? p1.y : (qq == 2) ? p1.z : p1.w;
                    float4 c0 = ((const float4*)(&ctx_s[4 * tl4 + qq][0]))[g];
                    a0[0] += f0 * c0.x; a0[1] += f0 * c0.y;
                    a0[2] += f0 * c0.z; a0[3] += f0 * c0.w;
                    a1[0] += f1 * c0.x; a1[1] += f1 * c0.y;
                    a1[2] += f1 * c0.z; a1[3] += f1 * c0.w;
                }
            }
        }
    }

    if (tid < 256) {
        float* orow0 = out + ((size_t)(b * U_ + mytile * UT) + u2) * D_;
        float* orow1 = out + ((size_t)(b * U_ + mytile * UT) + u2 + 8) * D_;
        *(float4*)(orow0 + 4 * g) = make_float4(a0[0], a0[1], a0[2], a0[3]);
        *(float4*)(orow1 + 4 * g) = make_float4(a1[0], a1[1], a1[2], a1[3]);
    }
}

extern "C" void kernel_launch(void* const* d_in, const int* in_sizes, int n_in,
                              void* d_out, int out_size, void* d_ws, size_t ws_size,
                              hipStream_t stream) {
    const float* h_t  = (const float*)d_in[0];
    const float* ctx  = (const float*)d_in[1];
    const float* mask = (const float*)d_in[2];
    const float* W    = (const float*)d_in[3];
    const float* bias = (const float*)d_in[4];
    float* out = (float*)d_out;
    unsigned long long* Tg = (unsigned long long*)d_ws;  // B*NT2*K u64 = 20 KB

    fused_kernel<<<dim3(B_ * NT2), dim3(512), 0, stream>>>(
        h_t, ctx, mask, W, bias, out, Tg);
}